// Round 8
// baseline (205.144 us; speedup 1.0000x reference)
//
#include <hip/hip_runtime.h>
#include <hip/hip_bf16.h>
#include <math.h>

typedef __attribute__((ext_vector_type(8))) short bfrag;   // 8 bf16 (16B)
typedef __attribute__((ext_vector_type(4))) float ffrag;   // mfma acc
typedef __attribute__((ext_vector_type(4))) float f4v;

#define C3 1536   // 3*H*D
#define PS 24     // P LDS row stride (shorts): 48B rows, 16B-aligned

__device__ __forceinline__ unsigned short f2bf(float f) {
    unsigned u = __float_as_uint(f);
    return (unsigned short)((u + 0x7FFFu + ((u >> 16) & 1u)) >> 16);  // RNE
}
__device__ __forceinline__ float bf2f(unsigned short s) {
    return __uint_as_float(((unsigned)s) << 16);
}

// sum over the 16 lanes of a DPP row: quad_perm xor1, xor2 + row_ror:4 + row_ror:8
__device__ __forceinline__ float row16_sum(float x) {
    int v;
    v = __builtin_amdgcn_update_dpp(0, __float_as_int(x), 0xB1, 0xF, 0xF, true);
    x += __int_as_float(v);
    v = __builtin_amdgcn_update_dpp(0, __float_as_int(x), 0x4E, 0xF, 0xF, true);
    x += __int_as_float(v);
    v = __builtin_amdgcn_update_dpp(0, __float_as_int(x), 0x124, 0xF, 0xF, true);
    x += __int_as_float(v);
    v = __builtin_amdgcn_update_dpp(0, __float_as_int(x), 0x128, 0xF, 0xF, true);
    x += __int_as_float(v);
    return x;
}

// ---------- kernel 1: cqkv bf16 table (cq pre-scaled by 1/8, blocks 0..1535)
//            + pqkv f32 / pbf bf16 (blocks 1536..1631: (l,cc) split) + gbtab ----------
__global__ __launch_bounds__(256) void precompute_kernel(
    const float* __restrict__ char_emb, const float* __restrict__ Wc, const float* __restrict__ bc,
    const float* __restrict__ Wp, const float* __restrict__ bp,
    const float* __restrict__ gamma, const float* __restrict__ beta,
    unsigned short* __restrict__ cqkv, float* __restrict__ pqkv,
    unsigned short* __restrict__ pbf, float* __restrict__ gbtab)
{
    const int b = blockIdx.x;
    const int t = threadIdx.x;
    if (b < 1536) {
        const int mt = b / 6;
        const int nt = b - mt * 6;
        const int m0 = mt * 8;
        const int c = nt * 256 + t;
        const float qs = (c < 512) ? 0.125f : 1.f;   // bake 1/TEMP into q (exact in bf16)
        const float bias = bc[c];
        float acc[8];
        #pragma unroll
        for (int r = 0; r < 8; ++r) acc[r] = bias;
        #pragma unroll 16
        for (int dd = 0; dd < 64; ++dd) {
            const float wv = Wc[dd * C3 + c];           // per-lane, coalesced, L2-hot
            #pragma unroll
            for (int r = 0; r < 8; ++r)
                acc[r] = fmaf(char_emb[(m0 + r) * 64 + dd], wv, acc[r]);  // uniform -> s_load
        }
        #pragma unroll
        for (int r = 0; r < 8; ++r)
            cqkv[(size_t)(m0 + r) * C3 + c] = f2bf(acc[r] * qs);
    } else {                             // pqkv: one (l, cc) pair per block
        const int e = b - 1536;
        const int l = e / 6;
        const int cc = e - l * 6;
        if (b == 1536 && t < 64) {       // gbtab[n][0..3]=gamma dt, [4..7]=beta dt
            #pragma unroll
            for (int dt = 0; dt < 4; ++dt) {
                gbtab[t * 8 + dt]     = gamma[dt * 16 + t];
                gbtab[t * 8 + 4 + dt] = beta[dt * 16 + t];
            }
        }
        __shared__ float spos[64];
        if (t < 64) {
            const int f = t & 31;
            const float inv = exp2f(-(float)f * 0.41524101186092034f);
            const float ph = (float)l * inv;
            spos[t] = (t < 32) ? cosf(ph) : sinf(ph);
        }
        __syncthreads();
        const int c = t + cc * 256;
        float acc = bp[c];
        #pragma unroll
        for (int dd = 0; dd < 64; ++dd)
            acc = fmaf(spos[dd], Wp[dd * C3 + c], acc);
        pqkv[l * C3 + c] = acc;
        if (c < 1024) {                  // pq/pk bf16 table: [(s*8+h)][l][d], pq pre-scaled
            const float qs = (c < 512) ? 0.125f : 1.f;
            pbf[(c >> 6) * 1024 + l * 64 + (c & 63)] = f2bf(acc * qs);
        }
    }
}

// ---------- kernel 1b: V' table (blocks 0..2047) + posqk C-layout table (blocks 2048..2055) ----------
__global__ __launch_bounds__(256) void vprime_kernel(
    const unsigned short* __restrict__ cqkv, const float* __restrict__ pqkv,
    unsigned short* __restrict__ vtab, float* __restrict__ posqk)
{
    const int c = blockIdx.x;
    const int t = threadIdx.x;
    if (c >= 2048) {                     // posqk[h][i][j] = 0.125 * pq_i . pk_j (f32)
        const int h = c - 2048;
        const int i = t >> 4, j = t & 15;
        const f4v* qa = (const f4v*)(pqkv + i * C3 + h * 64);
        const f4v* kb = (const f4v*)(pqkv + j * C3 + 512 + h * 64);
        float acc = 0.f;
        #pragma unroll
        for (int x = 0; x < 16; ++x) {
            const f4v a = qa[x], bb = kb[x];
            acc = fmaf(a[0], bb[0], acc);
            acc = fmaf(a[1], bb[1], acc);
            acc = fmaf(a[2], bb[2], acc);
            acc = fmaf(a[3], bb[3], acc);
        }
        // C-frag layout: [h][quad=i>>2][n=j][r=i&3]
        posqk[h * 256 + (i >> 2) * 64 + j * 4 + (i & 3)] = acc * 0.125f;
        return;
    }
    const int hd8 = t & 63;      // octet of (h*64+d)
    const int l0 = t >> 6;       // 0..3
    const bfrag cv = *(const bfrag*)(cqkv + (size_t)c * C3 + 1024 + hd8 * 8);
    #pragma unroll
    for (int li = 0; li < 4; ++li) {
        const int l = l0 + li * 4;
        const f4v pa = *(const f4v*)(pqkv + l * C3 + 1024 + hd8 * 8);
        const f4v pb = *(const f4v*)(pqkv + l * C3 + 1024 + hd8 * 8 + 4);
        bfrag o;
        #pragma unroll
        for (int j = 0; j < 8; ++j)
            o[j] = (short)f2bf(bf2f((unsigned short)cv[j]) + ((j < 4) ? pa[j] : pb[j - 4]));
        *(bfrag*)(vtab + ((size_t)c * 16 + l) * 512 + hd8 * 8) = o;
    }
}

// ---------- kernel 2: wave-per-(word,head) attention + LN + pool (NO barriers) ----------
__global__ __launch_bounds__(256, 8) void attn_kernel(
    const unsigned short* __restrict__ cqkv, const unsigned short* __restrict__ pbf,
    const unsigned short* __restrict__ vtab, const int* __restrict__ char_code,
    const float* __restrict__ posqk, const float* __restrict__ gbtab,
    float* __restrict__ pooled)
{
    __shared__ __attribute__((aligned(16))) unsigned short sVt[4 * 1024];   // per-wave 2KB
    __shared__ __attribute__((aligned(16))) unsigned short sP[4 * 16 * PS]; // per-wave 768B

    const int t = threadIdx.x;
    const int lane = t & 63;
    const int wid = t >> 6;
    const int gw = blockIdx.x * 4 + wid;
    const int w = gw >> 3;
    const int h = gw & 7;
    const int quad = lane >> 4;
    const int n = lane & 15;

    const int code = char_code[w * 16 + n];
    const bool kvalid = (code != 0);
    const unsigned long long msk = __ballot(kvalid);
    const int nv = __popcll(msk & 0xFFFFull);

    const f4v g4 = *(const f4v*)(gbtab + n * 8);
    const f4v b4 = *(const f4v*)(gbtab + n * 8 + 4);

    // ---- stage V' (already fused cv+pv) into wave-private swizzled tile ----
    unsigned short* vt = sVt + wid * 1024;
    #pragma unroll
    for (int cc = 0; cc < 2; ++cc) {
        const int d8 = quad + cc * 4;
        const bfrag vb = *(const bfrag*)(vtab + ((size_t)code * 16 + n) * 512 + h * 64 + d8 * 8);
        #pragma unroll
        for (int j = 0; j < 8; ++j) {
            const int d = d8 * 8 + j;
            const int e = ((d >> 4) * 2 + (n >> 3)) * 128
                        + ((d & 15) ^ ((n >> 3) << 2)) * 8 + (n & 7);
            vt[e] = (unsigned short)vb[j];
        }
    }

    // ---- S = cq'·ck + cq'·pk + ck·pq' + posqk(C-init)  (1/TEMP pre-baked) ----
    ffrag accS = *(const ffrag*)(posqk + h * 256 + quad * 64 + n * 4);
    {
        const unsigned short* cbase = cqkv + (size_t)code * C3 + h * 64;
        const unsigned short* pq = pbf + h * 1024 + n * 64;
        const unsigned short* pk = pbf + (8 + h) * 1024 + n * 64;
        #pragma unroll
        for (int cc = 0; cc < 2; ++cc) {
            const int off = quad * 8 + cc * 32;
            const bfrag cqF = *(const bfrag*)(cbase + off);
            const bfrag ckF = *(const bfrag*)(cbase + 512 + off);
            const bfrag pqF = *(const bfrag*)(pq + off);
            const bfrag pkF = *(const bfrag*)(pk + off);
            accS = __builtin_amdgcn_mfma_f32_16x16x32_bf16(cqF, ckF, accS, 0, 0, 0);
            accS = __builtin_amdgcn_mfma_f32_16x16x32_bf16(cqF, pkF, accS, 0, 0, 0);
            accS = __builtin_amdgcn_mfma_f32_16x16x32_bf16(ckF, pqF, accS, 0, 0, 0);
        }
    }

    // ---- softmax (no max-sub, logits ~1e-5), UNNORMALIZED P (1/sm cancels in LN) ----
    unsigned short* pt = sP + wid * 16 * PS;
    #pragma unroll
    for (int r = 0; r < 4; ++r) {
        const float pr = kvalid ? __expf(accS[r]) : 0.f;
        pt[(quad * 4 + r) * PS + n] = f2bf(pr);
    }

    // ---- O = P V  (K=16 zero-padded: quads 2,3 use zero A-frag) ----
    bfrag ap;
    #pragma unroll
    for (int j = 0; j < 8; ++j) ap[j] = 0;
    if (quad < 2) ap = *(const bfrag*)(pt + n * PS + quad * 8);
    const int q2 = quad & 1;
    ffrag accO[4];
    #pragma unroll
    for (int dt = 0; dt < 4; ++dt) { ffrag z = {0.f,0.f,0.f,0.f}; accO[dt] = z; }
    #pragma unroll
    for (int dt = 0; dt < 4; ++dt) {
        const bfrag bv = *(const bfrag*)(vt + (dt * 2 + q2) * 128 + (n ^ (q2 << 2)) * 8);
        accO[dt] = __builtin_amdgcn_mfma_f32_16x16x32_bf16(ap, bv, accO[dt], 0, 0, 0);
    }
    // row sums sm[i] via ones-MFMA: broadcast over n in C-layout, replaces 4 DPP chains
    bfrag onesf;
    #pragma unroll
    for (int j = 0; j < 8; ++j) onesf[j] = (short)0x3F80;
    ffrag accE = {0.f, 0.f, 0.f, 0.f};
    accE = __builtin_amdgcn_mfma_f32_16x16x32_bf16(ap, onesf, accE, 0, 0, 0);

    // ---- LayerNorm over D (O = sm * O_ref; eps scaled by sm^2) + masked pool over i ----
    float ps1[4], ps2[4];
    #pragma unroll
    for (int r = 0; r < 4; ++r) {
        ps1[r] = accO[0][r] + accO[1][r] + accO[2][r] + accO[3][r];
        ps2[r] = accO[0][r]*accO[0][r] + accO[1][r]*accO[1][r]
               + accO[2][r]*accO[2][r] + accO[3][r]*accO[3][r];
        ps1[r] = row16_sum(ps1[r]);
        ps2[r] = row16_sum(ps2[r]);
    }
    float pool[4] = {0.f, 0.f, 0.f, 0.f};
    #pragma unroll
    for (int r = 0; r < 4; ++r) {
        const float mu   = ps1[r] * 0.015625f;
        const float var  = fmaxf(ps2[r] * 0.015625f - mu * mu, 0.f);
        const float rstd = rsqrtf(var + accE[r] * accE[r] * 1e-5f);
        const float iv = ((msk >> (quad * 4 + r)) & 1ull) ? 1.f : 0.f;
        #pragma unroll
        for (int dt = 0; dt < 4; ++dt)
            pool[dt] += iv * fmaf((accO[dt][r] - mu) * rstd, g4[dt], b4[dt]);
    }
    #pragma unroll
    for (int xm = 16; xm <= 32; xm <<= 1) {
        #pragma unroll
        for (int dt = 0; dt < 4; ++dt) pool[dt] += __shfl_xor(pool[dt], xm);
    }
    if (quad == 0) {
        const float invnv = 1.f / (float)nv;
        f4v o;
        #pragma unroll
        for (int dt = 0; dt < 4; ++dt) o[dt] = pool[dt] * invnv;
        *(f4v*)(pooled + (size_t)w * 512 + h * 64 + n * 4) = o;   // [w][h][n][dt]
    }
}

// ---------- kernel 3: per-name fused MLP + word average (block per name, inline prefix) ----------
__global__ __launch_bounds__(128) void mlp_avg_kernel(
    const float* __restrict__ pooled, const int* __restrict__ word_code,
    const int* __restrict__ n_words,
    const float* __restrict__ W1, const float* __restrict__ b1,
    const float* __restrict__ W2, const float* __restrict__ b2,
    float* __restrict__ out)
{
    __shared__ float sPool[512];
    __shared__ float sHid[64 * 17];
    __shared__ float sWb[280];   // W1(128) b1(16) W2(128) b2(8)
    __shared__ int sred[128];
    const int nm = blockIdx.x;
    const int t = threadIdx.x;
    sWb[t] = W1[t];
    sWb[144 + t] = W2[t];
    if (t < 16) sWb[128 + t] = b1[t];
    if (t < 8)  sWb[272 + t] = b2[t];

    // inline exclusive prefix: off = sum_{i<nm} n_words[i]
    int part = 0;
    for (int i = t; i < nm; i += 128) part += n_words[i];
    sred[t] = part;
    __syncthreads();
    for (int s = 64; s > 0; s >>= 1) {
        if (t < s) sred[t] += sred[t + s];
        __syncthreads();
    }
    const int off = sred[0];
    const int cnt = n_words[nm];

    const int d = t & 63, o4 = (t >> 6) * 4;
    const int dmap = (d & 15) * 4 + (d >> 4);   // pooled layout [h][n][dt]
    float xacc[4] = {0.f, 0.f, 0.f, 0.f};

    for (int r = 0; r < cnt; ++r) {
        const int wc = word_code[off + r];
        __syncthreads();
        *(f4v*)(sPool + t * 4) = *(const f4v*)(pooled + (size_t)wc * 512 + t * 4);
        __syncthreads();
        if (t < 64) {
            float pl[8];
            #pragma unroll
            for (int hh = 0; hh < 8; ++hh) pl[hh] = sPool[hh * 64 + dmap];
            #pragma unroll
            for (int c = 0; c < 16; ++c) {
                float hs = sWb[128 + c];
                #pragma unroll
                for (int hh = 0; hh < 8; ++hh) hs = fmaf(pl[hh], sWb[hh * 16 + c], hs);
                sHid[t * 17 + c] = fmaxf(hs, 0.f);
            }
        }
        __syncthreads();
        #pragma unroll
        for (int c = 0; c < 16; ++c) {
            const float hc = sHid[d * 17 + c];
            #pragma unroll
            for (int oo = 0; oo < 4; ++oo)
                xacc[oo] = fmaf(hc, sWb[144 + c * 8 + o4 + oo], xacc[oo]);
        }
    }
    const float inv = 1.f / (float)cnt;
    f4v res;
    #pragma unroll
    for (int oo = 0; oo < 4; ++oo) res[oo] = xacc[oo] * inv + sWb[272 + o4 + oo];
    *(f4v*)(out + (size_t)nm * 512 + d * 8 + o4) = res;
}

extern "C" void kernel_launch(void* const* d_in, const int* in_sizes, int n_in,
                              void* d_out, int out_size, void* d_ws, size_t ws_size,
                              hipStream_t stream) {
    (void)in_sizes; (void)n_in; (void)out_size; (void)ws_size;
    const float* char_emb = (const float*)d_in[0];
    const float* Wc    = (const float*)d_in[1];
    const float* bc    = (const float*)d_in[2];
    const float* Wp    = (const float*)d_in[3];
    const float* bp    = (const float*)d_in[4];
    const float* gamma = (const float*)d_in[5];
    const float* beta  = (const float*)d_in[6];
    const float* W1    = (const float*)d_in[7];
    const float* b1    = (const float*)d_in[8];
    const float* W2    = (const float*)d_in[9];
    const float* b2    = (const float*)d_in[10];
    const int* char_code = (const int*)d_in[11];
    const int* word_code = (const int*)d_in[12];
    const int* n_words   = (const int*)d_in[13];   // harness passes ints as int32

    char* ws = (char*)d_ws;
    unsigned short* cqkv = (unsigned short*)ws;                        //  6,291,456 B
    float* pqkv = (float*)(ws + 6291456);                              //     98,304 B
    unsigned short* pbf  = (unsigned short*)(ws + 6389760);            //     32,768 B
    unsigned short* vtab = (unsigned short*)(ws + 6422528);            // 33,554,432 B
    float* pooled = (float*)(ws + 39976960);                           // 16,777,216 B
    float* posqk  = (float*)(ws + 56754176);                           //      8,192 B
    float* gbtab  = (float*)(ws + 56762368);                           //      2,048 B
    float* out = (float*)d_out;

    precompute_kernel<<<1632, 256, 0, stream>>>(char_emb, Wc, bc, Wp, bp, gamma, beta,
                                                cqkv, pqkv, pbf, gbtab);
    vprime_kernel<<<2056, 256, 0, stream>>>(cqkv, pqkv, vtab, posqk);
    attn_kernel<<<16384, 256, 0, stream>>>(cqkv, pbf, vtab, char_code, posqk, gbtab, pooled);
    mlp_avg_kernel<<<2048, 128, 0, stream>>>(pooled, word_code, n_words,
                                             W1, b1, W2, b2, out);
}